// Round 2
// baseline (3330.821 us; speedup 1.0000x reference)
//
#include <hip/hip_runtime.h>
#include <hip/hip_bf16.h>
#include <hip/hip_cooperative_groups.h>

namespace cg = cooperative_groups;

typedef __bf16 v8bf __attribute__((ext_vector_type(8)));
typedef float  v4f  __attribute__((ext_vector_type(4)));
typedef unsigned short u16;
typedef unsigned int   u32;

#define GAS __attribute__((address_space(1)))
#define LAS __attribute__((address_space(3)))

constexpr int C_ = 512;
constexpr int S_ = 3136;        // 56*56
constexpr int B_ = 32;
constexpr int M_ = B_ * S_;     // 100352
constexpr float INV_M = 1.0f / (float)M_;

__device__ __forceinline__ void async16(const u16* g, u16* l) {
  __builtin_amdgcn_global_load_lds((const GAS u32*)g, (LAS u32*)l, 16, 0, 0);
}

__device__ __forceinline__ u16 f2bf(float f) {   // RTNE fp32 -> bf16
  u32 u = __builtin_bit_cast(u32, f);
  u += 0x7fffu + ((u >> 16) & 1u);
  return (u16)(u >> 16);
}
__device__ __forceinline__ float bf2f(u16 h) {
  return __builtin_bit_cast(float, (u32)h << 16);
}

// ---------------------------------------------------------------------------
// K1: read X (B,C,S) fp32; write xbf (C, M) bf16 and xbfT (M, C) bf16;
//     accumulate per-channel sums. 64x64 (c,s) tile per block, one b per z.
// ---------------------------------------------------------------------------
__global__ __launch_bounds__(256) void prep_kernel(const float* __restrict__ X,
        u16* __restrict__ xbf, u16* __restrict__ xbfT, float* __restrict__ chsum) {
  __shared__ u16 Ts[64 * 65];
  const int tid = threadIdx.x;
  const int s0 = blockIdx.x * 64;
  const int c0 = blockIdx.y * 64;
  const int b  = blockIdx.z;

  const int i  = tid >> 2;
  const int jc = (tid & 3) * 16;
  const float* xp = X + (b * C_ + c0 + i) * S_ + s0 + jc;
  u16* op = xbf + (c0 + i) * M_ + b * S_ + s0 + jc;
  float ssum = 0.f;
  #pragma unroll
  for (int u = 0; u < 4; ++u) {
    float4 xv = *(const float4*)(xp + u * 4);
    ssum += xv.x + xv.y + xv.z + xv.w;
    u16 e0 = f2bf(xv.x), e1 = f2bf(xv.y), e2 = f2bf(xv.z), e3 = f2bf(xv.w);
    *(ushort4*)(op + u * 4) = make_ushort4(e0, e1, e2, e3);
    const int lb = i * 65 + jc + u * 4;
    Ts[lb + 0] = e0; Ts[lb + 1] = e1; Ts[lb + 2] = e2; Ts[lb + 3] = e3;
  }
  ssum += __shfl_down(ssum, 2, 4);
  ssum += __shfl_down(ssum, 1, 4);
  if ((tid & 3) == 0) atomicAdd(&chsum[c0 + i], ssum);
  __syncthreads();

  const int lane = tid & 63, wv = tid >> 6;
  #pragma unroll
  for (int p = 0; p < 2; ++p) {
    const int j  = p * 32 + wv * 8 + (lane >> 3);
    const int cc = (lane & 7) * 8;
    u16 tmp[8];
    #pragma unroll
    for (int e = 0; e < 8; ++e) tmp[e] = Ts[(cc + e) * 65 + j];
    u16* tp = xbfT + (b * S_ + s0 + j) * C_ + c0 + cc;
    *(ushort4*)(tp + 0) = make_ushort4(tmp[0], tmp[1], tmp[2], tmp[3]);
    *(ushort4*)(tp + 4) = make_ushort4(tmp[4], tmp[5], tmp[6], tmp[7]);
  }
}

// ---------------------------------------------------------------------------
// K2: Sigma partials. NT GEMM: part[z][i][j] = sum_{k in slice z} x[i,k]x[j,k]
// ---------------------------------------------------------------------------
__global__ __launch_bounds__(256, 2) void sigma_gemm(const u16* __restrict__ xbf,
                                                     float* __restrict__ part) {
  __shared__ u16 As[128 * 64];
  __shared__ u16 Bs[128 * 64];
  const int tid = threadIdx.x;
  const int tj = blockIdx.x, ti = blockIdx.y, z = blockIdx.z;
  const int kbase = z * S_;
  const int srow = tid >> 3;
  const int scol = (tid & 7) * 8;
  const int lane = tid & 63, wv = tid >> 6;
  const int wm = (wv & 1) * 64, wn = (wv >> 1) * 64;
  const int lr = lane & 15, lq = lane >> 4;
  const u16* gA = xbf + (ti * 128) * M_ + kbase + scol;
  const u16* gB = xbf + (tj * 128) * M_ + kbase + scol;
  v4f acc[4][4] = {};
  for (int it = 0; it < 49; ++it) {
    const int k0 = it * 64;
    #pragma unroll
    for (int q = 0; q < 4; ++q) {
      const int r = q * 32 + srow;
      async16(gA + r * M_ + k0, &As[r * 64 + scol]);
      async16(gB + r * M_ + k0, &Bs[r * 64 + scol]);
    }
    __syncthreads();
    #pragma unroll
    for (int kk = 0; kk < 2; ++kk) {
      v8bf a[4], b[4];
      #pragma unroll
      for (int x = 0; x < 4; ++x) a[x] = *(const v8bf*)&As[(wm + x*16 + lr)*64 + kk*32 + lq*8];
      #pragma unroll
      for (int x = 0; x < 4; ++x) b[x] = *(const v8bf*)&Bs[(wn + x*16 + lr)*64 + kk*32 + lq*8];
      #pragma unroll
      for (int mi = 0; mi < 4; ++mi)
        #pragma unroll
        for (int ni = 0; ni < 4; ++ni)
          acc[mi][ni] = __builtin_amdgcn_mfma_f32_16x16x32_bf16(a[mi], b[ni], acc[mi][ni], 0, 0, 0);
    }
    __syncthreads();
  }
  float* op = part + z * (C_ * C_);
  #pragma unroll
  for (int mi = 0; mi < 4; ++mi) {
    const int gi = ti * 128 + wm + mi * 16 + lq * 4;
    #pragma unroll
    for (int ni = 0; ni < 4; ++ni) {
      const int gj = tj * 128 + wn + ni * 16 + lr;
      #pragma unroll
      for (int r = 0; r < 4; ++r)
        op[(gi + r) * C_ + gj] = acc[mi][ni][r];
    }
  }
}

// ---------------------------------------------------------------------------
// K3 (cooperative): Sigma reduce + trace, SN/P init (split bf16), 10 NS
// iterations via split-bf16 MFMA (3 terms: hh + hl + lh), M2 = rot@P*sqrt(rtr),
// v = M2 @ mean. All matrices symmetric (polynomials of SN) -> B operands read
// rows directly. 512 blocks x 256 threads, 2 blocks/CU co-resident.
// ---------------------------------------------------------------------------
struct CoopArgs {
  const float* part; const float* chsum; const float* rotf; const int* Tptr;
  float* trace; float* Sigma;
  u16 *SNh, *SNl, *Ph, *Pl, *T1h, *T1l, *T2h, *T2l;
  float* Pf; u16 *roth, *rotl; float* M2f; u16* M2bf; float* v;
};

__global__ __launch_bounds__(256, 2) void ns_coop(CoopArgs A) {
  cg::grid_group grid = cg::this_grid();
  __shared__ float comb[2][256];
  const int tid = threadIdx.x;
  const int b = blockIdx.x;              // 512 blocks
  const int lane = tid & 63, wv = tid >> 6;
  const int gw = b * 4 + wv;             // 0..2047
  const int lr = lane & 15, lq = lane >> 4;

  // ---- stage 0: Sigma row b; trace via atomics (part still live here) ----
  {
    const float mb = A.chsum[b] * INV_M;
    for (int c = tid; c < 512; c += 256) {
      float s = 0.f;
      #pragma unroll 8
      for (int z = 0; z < 32; ++z) s += A.part[z * 262144 + b * 512 + c];
      float val = s * INV_M - mb * (A.chsum[c] * INV_M);
      if (c == b) { val += 1e-5f; atomicAdd(A.trace, val); }
      A.Sigma[b * 512 + c] = val;
    }
  }
  __threadfence();
  grid.sync();
  const float rtr = 1.0f / A.trace[0];

  // ---- stage 0b: SN = Sigma*rtr split; P = I; rot split ----
  for (int c = tid; c < 512; c += 256) {
    const int idx = b * 512 + c;
    float sn = A.Sigma[idx] * rtr;
    u16 h = f2bf(sn); A.SNh[idx] = h; A.SNl[idx] = f2bf(sn - bf2f(h));
    float pv = (b == c) ? 1.0f : 0.f;
    A.Pf[idx] = pv; A.Ph[idx] = f2bf(pv); A.Pl[idx] = 0;
    float rv = A.rotf[idx];
    u16 rh = f2bf(rv); A.roth[idx] = rh; A.rotl[idx] = f2bf(rv - bf2f(rh));
  }
  __threadfence();
  grid.sync();

  const int T = A.Tptr[0];
  for (int it = 0; it < T; ++it) {
    // ---- phase A: wave -> one 16x16 tile of T1=P@P (sel=0) or T2=P@SN ----
    {
      const int sel = gw >> 10, t = gw & 1023;
      const int tr = t >> 5, tc = t & 31;
      const u16* pa  = A.Ph + (tr * 16 + lr) * 512 + lq * 8;
      const u16* pal = A.Pl + (tr * 16 + lr) * 512 + lq * 8;
      const u16* pb  = (sel ? A.SNh : A.Ph) + (tc * 16 + lr) * 512 + lq * 8;
      const u16* pbl = (sel ? A.SNl : A.Pl) + (tc * 16 + lr) * 512 + lq * 8;
      v4f acc = {0.f, 0.f, 0.f, 0.f};
      #pragma unroll 4
      for (int k = 0; k < 512; k += 32) {
        v8bf ah = *(const v8bf*)(pa + k);
        v8bf al = *(const v8bf*)(pal + k);
        v8bf bh = *(const v8bf*)(pb + k);
        v8bf bl = *(const v8bf*)(pbl + k);
        acc = __builtin_amdgcn_mfma_f32_16x16x32_bf16(ah, bh, acc, 0, 0, 0);
        acc = __builtin_amdgcn_mfma_f32_16x16x32_bf16(ah, bl, acc, 0, 0, 0);
        acc = __builtin_amdgcn_mfma_f32_16x16x32_bf16(al, bh, acc, 0, 0, 0);
      }
      u16* Dh = sel ? A.T2h : A.T1h;
      u16* Dl = sel ? A.T2l : A.T1l;
      #pragma unroll
      for (int r = 0; r < 4; ++r) {
        const int idx = (tr * 16 + lq * 4 + r) * 512 + tc * 16 + lr;
        float x = acc[r];
        u16 h = f2bf(x); Dh[idx] = h; Dl[idx] = f2bf(x - bf2f(h));
      }
    }
    __threadfence();
    grid.sync();
    // ---- phase B: U = T1@T2 (K-split 2 within block), P = 1.5P - 0.5U ----
    {
      const int t = gw >> 1, h = gw & 1;
      const int tr = t >> 5, tc = t & 31;
      const int kb = h * 256;
      const u16* pa  = A.T1h + (tr * 16 + lr) * 512 + kb + lq * 8;
      const u16* pal = A.T1l + (tr * 16 + lr) * 512 + kb + lq * 8;
      const u16* pb  = A.T2h + (tc * 16 + lr) * 512 + kb + lq * 8;  // T2 symmetric
      const u16* pbl = A.T2l + (tc * 16 + lr) * 512 + kb + lq * 8;
      v4f acc = {0.f, 0.f, 0.f, 0.f};
      #pragma unroll 4
      for (int k = 0; k < 256; k += 32) {
        v8bf ah = *(const v8bf*)(pa + k);
        v8bf al = *(const v8bf*)(pal + k);
        v8bf bh = *(const v8bf*)(pb + k);
        v8bf bl = *(const v8bf*)(pbl + k);
        acc = __builtin_amdgcn_mfma_f32_16x16x32_bf16(ah, bh, acc, 0, 0, 0);
        acc = __builtin_amdgcn_mfma_f32_16x16x32_bf16(ah, bl, acc, 0, 0, 0);
        acc = __builtin_amdgcn_mfma_f32_16x16x32_bf16(al, bh, acc, 0, 0, 0);
      }
      const int pair = wv >> 1;
      if (h == 1) *(v4f*)&comb[pair][lane * 4] = acc;
      __syncthreads();
      if (h == 0) {
        v4f o = *(const v4f*)&comb[pair][lane * 4];
        #pragma unroll
        for (int r = 0; r < 4; ++r) {
          const int idx = (tr * 16 + lq * 4 + r) * 512 + tc * 16 + lr;
          float nv = 1.5f * A.Pf[idx] - 0.5f * (acc[r] + o[r]);
          A.Pf[idx] = nv;
          u16 hh = f2bf(nv); A.Ph[idx] = hh; A.Pl[idx] = f2bf(nv - bf2f(hh));
        }
      }
    }
    __threadfence();
    grid.sync();
  }

  // ---- tail: M2 = rot @ P * sqrt(rtr) (K-split 2), fp32 + bf16 ----
  {
    const int t = gw >> 1, h = gw & 1;
    const int tr = t >> 5, tc = t & 31;
    const int kb = h * 256;
    const u16* pa  = A.roth + (tr * 16 + lr) * 512 + kb + lq * 8;
    const u16* pal = A.rotl + (tr * 16 + lr) * 512 + kb + lq * 8;
    const u16* pb  = A.Ph + (tc * 16 + lr) * 512 + kb + lq * 8;    // P symmetric
    const u16* pbl = A.Pl + (tc * 16 + lr) * 512 + kb + lq * 8;
    v4f acc = {0.f, 0.f, 0.f, 0.f};
    #pragma unroll 4
    for (int k = 0; k < 256; k += 32) {
      v8bf ah = *(const v8bf*)(pa + k);
      v8bf al = *(const v8bf*)(pal + k);
      v8bf bh = *(const v8bf*)(pb + k);
      v8bf bl = *(const v8bf*)(pbl + k);
      acc = __builtin_amdgcn_mfma_f32_16x16x32_bf16(ah, bh, acc, 0, 0, 0);
      acc = __builtin_amdgcn_mfma_f32_16x16x32_bf16(ah, bl, acc, 0, 0, 0);
      acc = __builtin_amdgcn_mfma_f32_16x16x32_bf16(al, bh, acc, 0, 0, 0);
    }
    const int pair = wv >> 1;
    if (h == 1) *(v4f*)&comb[pair][lane * 4] = acc;
    __syncthreads();
    if (h == 0) {
      v4f o = *(const v4f*)&comb[pair][lane * 4];
      const float sc = sqrtf(rtr);
      #pragma unroll
      for (int r = 0; r < 4; ++r) {
        const int idx = (tr * 16 + lq * 4 + r) * 512 + tc * 16 + lr;
        float val = (acc[r] + o[r]) * sc;
        A.M2f[idx] = val;
        A.M2bf[idx] = f2bf(val);
      }
    }
  }
  __threadfence();
  grid.sync();

  // ---- v[d] = sum_c M2[d,c] * mean[c] ----
  if (gw < 512) {
    const int d = gw;
    float s = 0.f;
    #pragma unroll
    for (int j = 0; j < 8; ++j) {
      const int c = lane + j * 64;
      s += A.M2f[d * 512 + c] * (A.chsum[c] * INV_M);
    }
    #pragma unroll
    for (int off = 32; off; off >>= 1) s += __shfl_down(s, off);
    if (lane == 0) A.v[d] = s;
  }
}

// ---------------------------------------------------------------------------
// K4: out[b,d,s] = sum_c M2bf[d,c] * xbfT[b*S+s, c] - v[d]
// ---------------------------------------------------------------------------
__global__ __launch_bounds__(256, 2) void out_gemm(const u16* __restrict__ Abf,
        const u16* __restrict__ Bt, const float* __restrict__ v, float* __restrict__ out) {
  __shared__ u16 As[128 * 64];
  __shared__ u16 Bs[128 * 64];
  const int tid = threadIdx.x;
  const int tn = blockIdx.x, td = blockIdx.y;
  const int srow = tid >> 3, scol = (tid & 7) * 8;
  const int lane = tid & 63, wv = tid >> 6;
  const int wm = (wv & 1) * 64, wn = (wv >> 1) * 64;
  const int lr = lane & 15, lq = lane >> 4;
  const u16* gA = Abf + (td * 128) * 512 + scol;
  const u16* gB = Bt + (tn * 128) * 512 + scol;
  v4f acc[4][4] = {};
  for (int it = 0; it < 8; ++it) {
    const int k0 = it * 64;
    #pragma unroll
    for (int q = 0; q < 4; ++q) {
      const int r = q * 32 + srow;
      async16(gA + r * 512 + k0, &As[r * 64 + scol]);
      async16(gB + r * 512 + k0, &Bs[r * 64 + scol]);
    }
    __syncthreads();
    #pragma unroll
    for (int kk = 0; kk < 2; ++kk) {
      v8bf a[4], b[4];
      #pragma unroll
      for (int x = 0; x < 4; ++x) a[x] = *(const v8bf*)&As[(wm + x*16 + lr)*64 + kk*32 + lq*8];
      #pragma unroll
      for (int x = 0; x < 4; ++x) b[x] = *(const v8bf*)&Bs[(wn + x*16 + lr)*64 + kk*32 + lq*8];
      #pragma unroll
      for (int mi = 0; mi < 4; ++mi)
        #pragma unroll
        for (int ni = 0; ni < 4; ++ni)
          acc[mi][ni] = __builtin_amdgcn_mfma_f32_16x16x32_bf16(a[mi], b[ni], acc[mi][ni], 0, 0, 0);
    }
    __syncthreads();
  }
  #pragma unroll
  for (int mi = 0; mi < 4; ++mi) {
    const int d0 = td * 128 + wm + mi * 16 + lq * 4;
    const float vd0 = v[d0 + 0], vd1 = v[d0 + 1], vd2 = v[d0 + 2], vd3 = v[d0 + 3];
    #pragma unroll
    for (int ni = 0; ni < 4; ++ni) {
      const unsigned mcol = tn * 128 + wn + ni * 16 + lr;
      const unsigned bb = mcol / 3136u;
      const unsigned ss = mcol - bb * 3136u;
      const int obase = (int)(bb * 512u) * 3136 + (int)ss;
      out[obase + (d0 + 0) * 3136] = acc[mi][ni][0] - vd0;
      out[obase + (d0 + 1) * 3136] = acc[mi][ni][1] - vd1;
      out[obase + (d0 + 2) * 3136] = acc[mi][ni][2] - vd2;
      out[obase + (d0 + 3) * 3136] = acc[mi][ni][3] - vd3;
    }
  }
}

// ---------------------------------------------------------------------------
extern "C" void kernel_launch(void* const* d_in, const int* in_sizes, int n_in,
                              void* d_out, int out_size, void* d_ws, size_t ws_size,
                              hipStream_t stream) {
  const float* X   = (const float*)d_in[0];
  const float* rot = (const float*)d_in[1];
  const int*   T   = (const int*)d_in[2];
  float* out = (float*)d_out;

  char* ws = (char*)d_ws;
  size_t off = 0;
  auto alloc = [&](size_t bytes) -> char* {
    char* p = ws + off;
    off += (bytes + 255) & ~(size_t)255;
    return p;
  };
  u16*   xbf   = (u16*)alloc((size_t)C_ * M_ * 2);       // 102.8 MB
  u16*   xbfT  = (u16*)alloc((size_t)M_ * C_ * 2);       // 102.8 MB
  float* part  = (float*)alloc((size_t)32 * C_ * C_ * 4); // 33.5 MB
  float* Sigma = (float*)alloc((size_t)C_ * C_ * 4);     // 1 MB
  float* chsum = (float*)alloc(2048);
  float* trace = (float*)alloc(256);
  float* v     = (float*)alloc(2048);
  (void)ws_size; (void)in_sizes; (void)n_in; (void)out_size;

  // NS scratch matrices aliased into `part` (dead after coop stage 0):
  constexpr size_t HMB = (size_t)C_ * C_ * 2;   // 0.5 MB (bf16 512x512)
  char* pr = (char*)part;
  u16*   SNh  = (u16*)(pr + 0 * HMB);
  u16*   SNl  = (u16*)(pr + 1 * HMB);
  u16*   Ph   = (u16*)(pr + 2 * HMB);
  u16*   Pl   = (u16*)(pr + 3 * HMB);
  u16*   T1h  = (u16*)(pr + 4 * HMB);
  u16*   T1l  = (u16*)(pr + 5 * HMB);
  u16*   T2h  = (u16*)(pr + 6 * HMB);
  u16*   T2l  = (u16*)(pr + 7 * HMB);
  float* Pf   = (float*)(pr + 8 * HMB);          // 1 MB
  u16*   roth = (u16*)(pr + 10 * HMB);
  u16*   rotl = (u16*)(pr + 11 * HMB);
  float* M2f  = (float*)(pr + 12 * HMB);         // 1 MB
  u16*   M2bf = (u16*)(pr + 14 * HMB);

  hipMemsetAsync(chsum, 0, 2048 + 256, stream);  // chsum + trace

  prep_kernel<<<dim3(49, 8, 32), 256, 0, stream>>>(X, xbf, xbfT, chsum);
  sigma_gemm<<<dim3(4, 4, 32), 256, 0, stream>>>(xbf, part);

  CoopArgs ca;
  ca.part = part; ca.chsum = chsum; ca.rotf = rot; ca.Tptr = T;
  ca.trace = trace; ca.Sigma = Sigma;
  ca.SNh = SNh; ca.SNl = SNl; ca.Ph = Ph; ca.Pl = Pl;
  ca.T1h = T1h; ca.T1l = T1l; ca.T2h = T2h; ca.T2l = T2l;
  ca.Pf = Pf; ca.roth = roth; ca.rotl = rotl; ca.M2f = M2f; ca.M2bf = M2bf;
  ca.v = v;
  void* params[] = { &ca };
  hipLaunchCooperativeKernel((void*)ns_coop, dim3(512), dim3(256), params, 0, stream);

  out_gemm<<<dim3(784, 4), 256, 0, stream>>>(M2bf, xbfT, v, out);
}